// Round 14
// baseline (441.373 us; speedup 1.0000x reference)
//
#include <hip/hip_runtime.h>
#include <hip/hip_bf16.h>
#include <stdint.h>

// ---------------------------------------------------------------------------
// MultiheadAttention (B=2,S=2048,E=2048,H=16,D=128), softcap=50, alpha=1
// Inputs FP32, output FP32, dict-order labels (proven r8-r13).
// Round 14: (1) attn KVBLK 64->32: LDS 54KB->27.5KB => 4 blocks/CU (was 2),
// attacking the phase-serialization diagnosed from r12/r13 nulls;
// (2) single merged cvt kernel (7 launches -> 1).
// GEMMs (m97 global_load_lds, ~840 TF) unchanged.
// ---------------------------------------------------------------------------

typedef __attribute__((ext_vector_type(8))) short s16x8;   // 8 bf16
typedef __attribute__((ext_vector_type(4))) short s16x4;   // 4 bf16
typedef __attribute__((ext_vector_type(4))) float f32x4;

typedef const __attribute__((address_space(1))) char* gcptr;
typedef __attribute__((address_space(3))) char* lcptr;

#define MFMA_BF16(a, b, c) __builtin_amdgcn_mfma_f32_16x16x32_bf16((a), (b), (c), 0, 0, 0)

__device__ __forceinline__ short f2bf(float f) {          // fp32 -> bf16 RNE
  union { float f; unsigned u; } x; x.f = f;
  unsigned r = (x.u + 0x7fffu + ((x.u >> 16) & 1u)) >> 16;
  return (short)r;
}

__device__ __forceinline__ void gload16(const void* g, void* lds) {
  __builtin_amdgcn_global_load_lds((gcptr)g, (lcptr)lds, 16, 0, 0);
}

constexpr int GM = 4096, GN = 2048, GK = 2048;
constexpr int SL = 2048, EMB = 2048, HD = 128;

// ---------------------------------------------------------------------------
// Merged fp32 -> bf16 conversion for all 7 inputs (dst contiguous in ws).
// n8a = 1<<20 chunks per activation, n8w = 1<<19 per weight (8 elems/chunk).
// ---------------------------------------------------------------------------
__global__ void cvt_all(const float* __restrict__ q, const float* __restrict__ k,
                        const float* __restrict__ v, const float* __restrict__ wq,
                        const float* __restrict__ wk, const float* __restrict__ wv,
                        const float* __restrict__ wo, short* __restrict__ dst) {
  const int N8A = 1 << 20, N8W = 1 << 19;
  const int total = 3 * N8A + 4 * N8W;       // 5,242,880 chunks
  int i = blockIdx.x * blockDim.x + threadIdx.x;
  int stride = gridDim.x * blockDim.x;
  for (; i < total; i += stride) {
    const float* src;
    size_t loc;
    if (i < 3 * N8A) {
      int sel = i >> 20;
      loc = (size_t)(i & (N8A - 1));
      src = sel == 0 ? q : (sel == 1 ? k : v);
    } else {
      int w = i - 3 * N8A;
      int sel = w >> 19;
      loc = (size_t)(w & (N8W - 1));
      src = sel == 0 ? wq : (sel == 1 ? wk : (sel == 2 ? wv : wo));
    }
    f32x4 a = *reinterpret_cast<const f32x4*>(src + loc * 8);
    f32x4 b = *reinterpret_cast<const f32x4*>(src + loc * 8 + 4);
    s16x8 w8;
#pragma unroll
    for (int j = 0; j < 4; ++j) { w8[j] = f2bf(a[j]); w8[4 + j] = f2bf(b[j]); }
    *reinterpret_cast<s16x8*>(dst + (size_t)i * 8) = w8;
  }
}

// ---------------------------------------------------------------------------
// Pure-bf16 GEMM, B-transposed, global_load_lds staging (m97 structure).
// ---------------------------------------------------------------------------
template <bool OF32>
__global__ __launch_bounds__(256, 2)
void gemm_bt_bf16(const short* __restrict__ A, const short* __restrict__ B,
                  void* __restrict__ Cv) {
  __shared__ __align__(16) short As[128 * 64];
  __shared__ __align__(16) short Bs[128 * 64];
  const int tid = threadIdx.x;
  const int lane = tid & 63;
  const int wid = tid >> 6;
  const int wr = wid >> 1, wc = wid & 1;
  const int g = lane >> 4, r = lane & 15;
  const int bm = blockIdx.y, bn = blockIdx.x;

  const f32x4 fz = {0.f, 0.f, 0.f, 0.f};
  f32x4 acc[4][4];
#pragma unroll
  for (int m = 0; m < 4; ++m)
#pragma unroll
    for (int n = 0; n < 4; ++n) acc[m][n] = fz;

  const short* Ab = A + (size_t)bm * 128 * GK;
  const short* Bb = B + (size_t)bn * 128 * GK;

  for (int kt = 0; kt < GK; kt += 64) {
#pragma unroll
    for (int i = 0; i < 4; ++i) {
      int c = i * 256 + tid;
      int row = c >> 3, c8 = c & 7;
      gload16(Ab + (size_t)row * GK + kt + c8 * 8, As + c * 8);
      gload16(Bb + (size_t)row * GK + kt + c8 * 8, Bs + c * 8);
    }
    __syncthreads();
#pragma unroll
    for (int kk = 0; kk < 2; ++kk) {
      s16x8 af[4], bf[4];
#pragma unroll
      for (int m = 0; m < 4; ++m)
        af[m] = *reinterpret_cast<const s16x8*>(As + (wr * 64 + m * 16 + r) * 64 + kk * 32 + g * 8);
#pragma unroll
      for (int n = 0; n < 4; ++n)
        bf[n] = *reinterpret_cast<const s16x8*>(Bs + (wc * 64 + n * 16 + r) * 64 + kk * 32 + g * 8);
#pragma unroll
      for (int m = 0; m < 4; ++m)
#pragma unroll
        for (int n = 0; n < 4; ++n) acc[m][n] = MFMA_BF16(af[m], bf[n], acc[m][n]);
    }
    __syncthreads();
  }

#pragma unroll
  for (int m = 0; m < 4; ++m)
#pragma unroll
    for (int j = 0; j < 4; ++j) {
      int crow = bm * 128 + wr * 64 + m * 16 + g * 4 + j;
      size_t off = (size_t)crow * GN + bn * 128 + wc * 64 + r;
#pragma unroll
      for (int n = 0; n < 4; ++n) {
        if constexpr (OF32) ((float*)Cv)[off + n * 16] = acc[m][n][j];
        else                ((short*)Cv)[off + n * 16] = f2bf(acc[m][n][j]);
      }
    }
}

// ---------------------------------------------------------------------------
// MFMA flash attention — 4 waves / 256 threads; 32 q-rows per wave; KVBLK=32.
// LDS 27.5KB => 4 blocks/CU. T14 prefetch. Fixed-max-50 + poly softcap +
// deferred l-reduce. V swizzle (32-col): store colsw = rr ^ ((c8&3)<<3),
// read col (g ^ ((d>>3)&3))*8 — exact inverses. grid (S/128, B*H).
// ---------------------------------------------------------------------------
__global__ __launch_bounds__(256, 4)
void attn(const short* __restrict__ Q, const short* __restrict__ K,
          const short* __restrict__ V, short* __restrict__ O) {
  __shared__ __align__(16) short Ks[32 * 136];
  __shared__ __align__(16) short Vt[128 * 40];
  __shared__ __align__(16) short Ps[4][2][16 * 36];

  const int tid = threadIdx.x;
  const int lane = tid & 63;
  const int wid = tid >> 6;                  // 0..3
  const int g = lane >> 4, r = lane & 15;
  const int qb = blockIdx.x;                 // 0..15
  const int bh = blockIdx.y;
  const int b = bh >> 4, h = bh & 15;
  const size_t base = (size_t)b * SL * EMB + (size_t)h * HD;

  const int q0 = qb * 128 + wid * 32;        // wave's first q-row (32 rows)
  s16x8 qf[2][4];
#pragma unroll
  for (int s = 0; s < 2; ++s)
#pragma unroll
    for (int kk = 0; kk < 4; ++kk)
      qf[s][kk] = *reinterpret_cast<const s16x8*>(
          Q + base + (size_t)(q0 + s * 16 + r) * EMB + kk * 32 + g * 8);

  const f32x4 fz = {0.f, 0.f, 0.f, 0.f};
  float l_run[2][4];
  f32x4 acc_o[2][8];
#pragma unroll
  for (int s = 0; s < 2; ++s) {
#pragma unroll
    for (int i = 0; i < 4; ++i) l_run[s][i] = 0.f;
#pragma unroll
    for (int i = 0; i < 8; ++i) acc_o[s][i] = fz;
  }

  const float SCALE = 0.08838834764831845f;  // 1/sqrt(128)
  const float C50I = 0.02f;                  // 1/50
  const float CA = -1.f / 3.f, CB = 2.f / 15.f;

  // ---- T14 prologue: tile 0 -> registers ----
  const int rr0 = tid >> 4, c8 = tid & 15;   // 32 rows x 16 chunks over 2 iters
  s16x8 kreg[2], vreg[2];
#pragma unroll
  for (int i = 0; i < 2; ++i) {
    int rr = rr0 + i * 16;
    kreg[i] = *reinterpret_cast<const s16x8*>(K + base + (size_t)rr * EMB + c8 * 8);
    vreg[i] = *reinterpret_cast<const s16x8*>(V + base + (size_t)rr * EMB + c8 * 8);
  }

  for (int t = 0; t < SL / 32; ++t) {
    __syncthreads();                         // prev tile's readers done
    // ---- write-late: regs -> LDS ----
    const int colswb = (c8 & 3) << 3;
#pragma unroll
    for (int i = 0; i < 2; ++i) {
      int rr = rr0 + i * 16;
      *reinterpret_cast<s16x8*>(&Ks[rr * 136 + c8 * 8]) = kreg[i];
      int colsw = rr ^ colswb;
#pragma unroll
      for (int j = 0; j < 8; ++j) Vt[(c8 * 8 + j) * 40 + colsw] = vreg[i][j];
    }
    __syncthreads();                         // staging visible

    // ---- issue-early: next tile's loads ----
    if (t + 1 < SL / 32) {
      const int kv1 = (t + 1) * 32;
#pragma unroll
      for (int i = 0; i < 2; ++i) {
        int rr = rr0 + i * 16;
        kreg[i] = *reinterpret_cast<const s16x8*>(K + base + (size_t)(kv1 + rr) * EMB + c8 * 8);
        vreg[i] = *reinterpret_cast<const s16x8*>(V + base + (size_t)(kv1 + rr) * EMB + c8 * 8);
      }
    }

    // ---- S = Q K^T : each kf read feeds both q-sets ----
    f32x4 sv[2][2];
#pragma unroll
    for (int kn = 0; kn < 2; ++kn) {
      sv[0][kn] = fz; sv[1][kn] = fz;
#pragma unroll
      for (int kk = 0; kk < 4; ++kk) {
        s16x8 kf = *reinterpret_cast<const s16x8*>(&Ks[(kn * 16 + r) * 136 + kk * 32 + g * 8]);
        sv[0][kn] = MFMA_BF16(qf[0][kk], kf, sv[0][kn]);
        sv[1][kn] = MFMA_BF16(qf[1][kk], kf, sv[1][kn]);
      }
    }

    // ---- poly softcap + fixed-max-50 softmax (lane-local) ----
#pragma unroll
    for (int s = 0; s < 2; ++s)
#pragma unroll
      for (int kn = 0; kn < 2; ++kn)
#pragma unroll
        for (int reg = 0; reg < 4; ++reg) {
          float z = sv[s][kn][reg] * SCALE;
          float x = z * C50I;
          float x2 = x * x;
          float poly = __builtin_fmaf(x2, __builtin_fmaf(x2, CB, CA), 1.f);
          float cap = fminf(z * poly, 50.f);
          float pe = __expf(cap - 50.f);
          l_run[s][reg] += pe;
          sv[s][kn][reg] = pe;
        }

    // ---- P -> LDS (bf16), wave-private, A-operand layout ----
#pragma unroll
    for (int s = 0; s < 2; ++s)
#pragma unroll
      for (int kn = 0; kn < 2; ++kn)
#pragma unroll
        for (int reg = 0; reg < 4; ++reg)
          Ps[wid][s][(g * 4 + reg) * 36 + kn * 16 + r] = f2bf(sv[s][kn][reg]);

    // ---- O += P V (single K=32 MFMA per dn per set) ----
    {
      s16x8 pa0 = *reinterpret_cast<const s16x8*>(&Ps[wid][0][r * 36 + g * 8]);
      s16x8 pa1 = *reinterpret_cast<const s16x8*>(&Ps[wid][1][r * 36 + g * 8]);
#pragma unroll
      for (int dn = 0; dn < 8; ++dn) {
        int d = dn * 16 + r;
        int e = ((dn * 2) + (r >> 3)) & 3;            // (d>>3)&3
        s16x8 vf = *reinterpret_cast<const s16x8*>(&Vt[d * 40 + ((g ^ e) * 8)]);
        acc_o[0][dn] = MFMA_BF16(pa0, vf, acc_o[0][dn]);
        acc_o[1][dn] = MFMA_BF16(pa1, vf, acc_o[1][dn]);
      }
    }
  }

  // ---- deferred l reduction + epilogue (both sets) ----
#pragma unroll
  for (int s = 0; s < 2; ++s) {
#pragma unroll
    for (int reg = 0; reg < 4; ++reg) {
#pragma unroll
      for (int off = 1; off < 16; off <<= 1)
        l_run[s][reg] += __shfl_xor(l_run[s][reg], off);
      l_run[s][reg] = 1.f / l_run[s][reg];
    }
#pragma unroll
    for (int dn = 0; dn < 8; ++dn)
#pragma unroll
      for (int reg = 0; reg < 4; ++reg) {
        int row = q0 + s * 16 + g * 4 + reg;
        O[base + (size_t)row * EMB + dn * 16 + r] = f2bf(acc_o[s][dn][reg] * l_run[s][reg]);
      }
  }
}

__global__ void fill_f32(float* p, int n, float val) {
  int i = blockIdx.x * blockDim.x + threadIdx.x;
  if (i < n) p[i] = val;
}

// ---------------------------------------------------------------------------
extern "C" void kernel_launch(void* const* d_in, const int* in_sizes, int n_in,
                              void* d_out, int out_size, void* d_ws, size_t ws_size,
                              hipStream_t stream) {
  const float* q  = (const float*)d_in[0];
  const float* k  = (const float*)d_in[1];
  const float* v  = (const float*)d_in[2];
  const float* wq = (const float*)d_in[3];
  const float* wk = (const float*)d_in[4];
  const float* wv = (const float*)d_in[5];
  const float* wo = (const float*)d_in[6];
  float* out = (float*)d_out;

  bool ok = (n_in == 7) && out_size == 8388608;
  for (int i = 0; i < 3 && ok; ++i) ok = (in_sizes[i] == 8388608);
  for (int i = 3; i < 7 && ok; ++i) ok = (in_sizes[i] == 4194304);
  if (!ok) {
    fill_f32<<<(out_size + 255) / 256, 256, 0, stream>>>(out, out_size, 150.f);
    return;
  }

  const size_t NA = 8388608;
  const size_t NW = 4194304;
  const size_t NE = (size_t)GM * GN;
  const size_t need = (3 * NA + 4 * NW + 4 * NE) * sizeof(short); // 144 MiB
  if (ws_size < need) {
    fill_f32<<<(out_size + 255) / 256, 256, 0, stream>>>(out, out_size, 128.f);
    return;
  }

  short* bq  = (short*)d_ws;                 // cvt dst, contiguous
  short* bk  = bq + NA;
  short* bv  = bk + NA;
  short* bwq = bv + NA;
  short* bwk = bwq + NW;
  short* bwv = bwk + NW;
  short* bwo = bwv + NW;
  short* Qp  = bwo + NW;
  short* Kp  = Qp + NE;
  short* Vp  = Kp + NE;
  short* Cx  = Vp + NE;

  dim3 blk(256);
  dim3 gg(GN / 128, GM / 128);               // (16, 32)
  dim3 ga(SL / 128, 32);                     // 512 blocks

  cvt_all<<<2048, 256, 0, stream>>>(q, k, v, wq, wk, wv, wo, bq);

  gemm_bt_bf16<false><<<gg, blk, 0, stream>>>(bq, bwq, Qp);
  gemm_bt_bf16<false><<<gg, blk, 0, stream>>>(bk, bwk, Kp);
  gemm_bt_bf16<false><<<gg, blk, 0, stream>>>(bv, bwv, Vp);
  attn<<<ga, blk, 0, stream>>>(Qp, Kp, Vp, Cx);
  gemm_bt_bf16<true><<<gg, blk, 0, stream>>>(Cx, bwo, out);
}

// Round 15
// 349.757 us; speedup vs baseline: 1.2619x; 1.2619x over previous
//
#include <hip/hip_runtime.h>
#include <hip/hip_bf16.h>
#include <stdint.h>

// ---------------------------------------------------------------------------
// MultiheadAttention (B=2,S=2048,E=2048,H=16,D=128), softcap=50, alpha=1
// Inputs FP32, output FP32, dict-order labels (proven r8-r14).
// Round 15: (1) revert attn to r13 structure (KVBLK=64; r14's KVBLK=32
// regressed: per-tile fixed cost dominates); (2) V-projection GEMM computes
// VpT = (v@Wv^T)^T directly by swapping GEMM operands (free) so attn's V
// staging is pure b128 (the 32-scalar-write transpose scatter, paid 16x per
// head, is gone). Chunk-XOR swizzle keeps banks ~2-way, b128 both sides.
// ---------------------------------------------------------------------------

typedef __attribute__((ext_vector_type(8))) short s16x8;   // 8 bf16
typedef __attribute__((ext_vector_type(4))) float f32x4;

typedef const __attribute__((address_space(1))) char* gcptr;
typedef __attribute__((address_space(3))) char* lcptr;

#define MFMA_BF16(a, b, c) __builtin_amdgcn_mfma_f32_16x16x32_bf16((a), (b), (c), 0, 0, 0)

__device__ __forceinline__ short f2bf(float f) {          // fp32 -> bf16 RNE
  union { float f; unsigned u; } x; x.f = f;
  unsigned r = (x.u + 0x7fffu + ((x.u >> 16) & 1u)) >> 16;
  return (short)r;
}

__device__ __forceinline__ void gload16(const void* g, void* lds) {
  __builtin_amdgcn_global_load_lds((gcptr)g, (lcptr)lds, 16, 0, 0);
}

constexpr int GK = 2048;
constexpr int SL = 2048, EMB = 2048, HD = 128;

// ---------------------------------------------------------------------------
// Merged fp32 -> bf16 conversion for all 7 inputs (dst contiguous in ws).
// ---------------------------------------------------------------------------
__global__ void cvt_all(const float* __restrict__ q, const float* __restrict__ k,
                        const float* __restrict__ v, const float* __restrict__ wq,
                        const float* __restrict__ wk, const float* __restrict__ wv,
                        const float* __restrict__ wo, short* __restrict__ dst) {
  const int N8A = 1 << 20, N8W = 1 << 19;
  const int total = 3 * N8A + 4 * N8W;
  int i = blockIdx.x * blockDim.x + threadIdx.x;
  int stride = gridDim.x * blockDim.x;
  for (; i < total; i += stride) {
    const float* src;
    size_t loc;
    if (i < 3 * N8A) {
      int sel = i >> 20;
      loc = (size_t)(i & (N8A - 1));
      src = sel == 0 ? q : (sel == 1 ? k : v);
    } else {
      int w = i - 3 * N8A;
      int sel = w >> 19;
      loc = (size_t)(w & (N8W - 1));
      src = sel == 0 ? wq : (sel == 1 ? wk : (sel == 2 ? wv : wo));
    }
    f32x4 a = *reinterpret_cast<const f32x4*>(src + loc * 8);
    f32x4 b = *reinterpret_cast<const f32x4*>(src + loc * 8 + 4);
    s16x8 w8;
#pragma unroll
    for (int j = 0; j < 4; ++j) { w8[j] = f2bf(a[j]); w8[4 + j] = f2bf(b[j]); }
    *reinterpret_cast<s16x8*>(dst + (size_t)i * 8) = w8;
  }
}

// ---------------------------------------------------------------------------
// Pure-bf16 GEMM, B-transposed, global_load_lds staging (m97 structure).
// C[m,n] = sum_k A[m,k]*B[n,k]; n-dim size `gn` is a runtime param so the
// same kernel computes VpT via swapped operands (A=Wv, B=v, gn=4096).
// ---------------------------------------------------------------------------
template <bool OF32>
__global__ __launch_bounds__(256, 2)
void gemm_bt_bf16(const short* __restrict__ A, const short* __restrict__ B,
                  void* __restrict__ Cv, int gn) {
  __shared__ __align__(16) short As[128 * 64];
  __shared__ __align__(16) short Bs[128 * 64];
  const int tid = threadIdx.x;
  const int lane = tid & 63;
  const int wid = tid >> 6;
  const int wr = wid >> 1, wc = wid & 1;
  const int g = lane >> 4, r = lane & 15;
  const int bm = blockIdx.y, bn = blockIdx.x;

  const f32x4 fz = {0.f, 0.f, 0.f, 0.f};
  f32x4 acc[4][4];
#pragma unroll
  for (int m = 0; m < 4; ++m)
#pragma unroll
    for (int n = 0; n < 4; ++n) acc[m][n] = fz;

  const short* Ab = A + (size_t)bm * 128 * GK;
  const short* Bb = B + (size_t)bn * 128 * GK;

  for (int kt = 0; kt < GK; kt += 64) {
#pragma unroll
    for (int i = 0; i < 4; ++i) {
      int c = i * 256 + tid;
      int row = c >> 3, c8 = c & 7;
      gload16(Ab + (size_t)row * GK + kt + c8 * 8, As + c * 8);
      gload16(Bb + (size_t)row * GK + kt + c8 * 8, Bs + c * 8);
    }
    __syncthreads();
#pragma unroll
    for (int kk = 0; kk < 2; ++kk) {
      s16x8 af[4], bf[4];
#pragma unroll
      for (int m = 0; m < 4; ++m)
        af[m] = *reinterpret_cast<const s16x8*>(As + (wr * 64 + m * 16 + r) * 64 + kk * 32 + g * 8);
#pragma unroll
      for (int n = 0; n < 4; ++n)
        bf[n] = *reinterpret_cast<const s16x8*>(Bs + (wc * 64 + n * 16 + r) * 64 + kk * 32 + g * 8);
#pragma unroll
      for (int m = 0; m < 4; ++m)
#pragma unroll
        for (int n = 0; n < 4; ++n) acc[m][n] = MFMA_BF16(af[m], bf[n], acc[m][n]);
    }
    __syncthreads();
  }

#pragma unroll
  for (int m = 0; m < 4; ++m)
#pragma unroll
    for (int j = 0; j < 4; ++j) {
      int crow = bm * 128 + wr * 64 + m * 16 + g * 4 + j;
      size_t off = (size_t)crow * gn + bn * 128 + wc * 64 + r;
#pragma unroll
      for (int n = 0; n < 4; ++n) {
        if constexpr (OF32) ((float*)Cv)[off + n * 16] = acc[m][n][j];
        else                ((short*)Cv)[off + n * 16] = f2bf(acc[m][n][j]);
      }
    }
}

// ---------------------------------------------------------------------------
// MFMA flash attention — 4 waves / 256 threads; 32 q-rows per wave; KVBLK=64.
// V comes pre-transposed (VpT[(h*128+d)][(b*2048+s)]) so staging is b128
// load -> b128 LDS write with chunk-XOR swizzle (phys = ch ^ (d&7)).
// T14 prefetch; fixed-max-50 + poly softcap + deferred l-reduce.
// ---------------------------------------------------------------------------
__global__ __launch_bounds__(256, 2)
void attn(const short* __restrict__ Q, const short* __restrict__ K,
          const short* __restrict__ VT, short* __restrict__ O) {
  __shared__ __align__(16) short Ks[64 * 136];
  __shared__ __align__(16) short Vt[128 * 72];
  __shared__ __align__(16) short Ps[4][2][16 * 72];

  const int tid = threadIdx.x;
  const int lane = tid & 63;
  const int wid = tid >> 6;                  // 0..3
  const int g = lane >> 4, r = lane & 15;
  const int qb = blockIdx.x;                 // 0..15
  const int bh = blockIdx.y;
  const int b = bh >> 4, h = bh & 15;
  const size_t base = (size_t)b * SL * EMB + (size_t)h * HD;
  const size_t vbase = (size_t)h * HD * 4096 + (size_t)b * SL;  // VpT origin

  const int q0 = qb * 128 + wid * 32;        // wave's first q-row (32 rows)
  s16x8 qf[2][4];
#pragma unroll
  for (int s = 0; s < 2; ++s)
#pragma unroll
    for (int kk = 0; kk < 4; ++kk)
      qf[s][kk] = *reinterpret_cast<const s16x8*>(
          Q + base + (size_t)(q0 + s * 16 + r) * EMB + kk * 32 + g * 8);

  const f32x4 fz = {0.f, 0.f, 0.f, 0.f};
  float l_run[2][4];
  f32x4 acc_o[2][8];
#pragma unroll
  for (int s = 0; s < 2; ++s) {
#pragma unroll
    for (int i = 0; i < 4; ++i) l_run[s][i] = 0.f;
#pragma unroll
    for (int i = 0; i < 8; ++i) acc_o[s][i] = fz;
  }

  const float SCALE = 0.08838834764831845f;  // 1/sqrt(128)
  const float C50I = 0.02f;                  // 1/50
  const float CA = -1.f / 3.f, CB = 2.f / 15.f;

  // ---- T14 prologue: tile 0 -> registers ----
  const int rk = tid >> 4, ck = tid & 15;    // K: [64 rows][16 chunks], 4 iters
  const int rv = tid >> 3, cv = tid & 7;     // V: [128 rows][8 chunks], 4 iters
  const int cvx = cv ^ (rv & 7);             // phys chunk for LDS write
  s16x8 kreg[4], vreg[4];
#pragma unroll
  for (int i = 0; i < 4; ++i) {
    kreg[i] = *reinterpret_cast<const s16x8*>(K + base + (size_t)(rk + i * 16) * EMB + ck * 8);
    vreg[i] = *reinterpret_cast<const s16x8*>(VT + vbase + (size_t)(rv + i * 32) * 4096 + cv * 8);
  }

  for (int t = 0; t < SL / 64; ++t) {
    __syncthreads();                         // prev tile's readers done
    // ---- write-late: regs -> LDS (all b128) ----
#pragma unroll
    for (int i = 0; i < 4; ++i) {
      *reinterpret_cast<s16x8*>(&Ks[(rk + i * 16) * 136 + ck * 8]) = kreg[i];
      *reinterpret_cast<s16x8*>(&Vt[(rv + i * 32) * 72 + (cvx << 3)]) = vreg[i];
    }
    __syncthreads();                         // staging visible

    // ---- issue-early: next tile's loads ----
    if (t + 1 < SL / 64) {
      const int kv1 = (t + 1) * 64;
#pragma unroll
      for (int i = 0; i < 4; ++i) {
        kreg[i] = *reinterpret_cast<const s16x8*>(K + base + (size_t)(kv1 + rk + i * 16) * EMB + ck * 8);
        vreg[i] = *reinterpret_cast<const s16x8*>(VT + vbase + (size_t)(rv + i * 32) * 4096 + kv1 + cv * 8);
      }
    }

    // ---- S = Q K^T : each kf read feeds both q-sets ----
    f32x4 sv[2][4];
#pragma unroll
    for (int kn = 0; kn < 4; ++kn) {
      sv[0][kn] = fz; sv[1][kn] = fz;
#pragma unroll
      for (int kk = 0; kk < 4; ++kk) {
        s16x8 kf = *reinterpret_cast<const s16x8*>(&Ks[(kn * 16 + r) * 136 + kk * 32 + g * 8]);
        sv[0][kn] = MFMA_BF16(qf[0][kk], kf, sv[0][kn]);
        sv[1][kn] = MFMA_BF16(qf[1][kk], kf, sv[1][kn]);
      }
    }

    // ---- poly softcap + fixed-max-50 softmax (lane-local) ----
#pragma unroll
    for (int s = 0; s < 2; ++s)
#pragma unroll
      for (int kn = 0; kn < 4; ++kn)
#pragma unroll
        for (int reg = 0; reg < 4; ++reg) {
          float z = sv[s][kn][reg] * SCALE;
          float x = z * C50I;
          float x2 = x * x;
          float poly = __builtin_fmaf(x2, __builtin_fmaf(x2, CB, CA), 1.f);
          float cap = fminf(z * poly, 50.f);
          float pe = __expf(cap - 50.f);
          l_run[s][reg] += pe;
          sv[s][kn][reg] = pe;
        }

    // ---- P -> LDS (bf16), wave-private, A-operand layout ----
#pragma unroll
    for (int s = 0; s < 2; ++s)
#pragma unroll
      for (int kn = 0; kn < 4; ++kn)
#pragma unroll
        for (int reg = 0; reg < 4; ++reg)
          Ps[wid][s][(g * 4 + reg) * 72 + kn * 16 + r] = f2bf(sv[s][kn][reg]);

    // ---- O += P V : each vf read feeds both q-sets ----
#pragma unroll
    for (int c = 0; c < 2; ++c) {
      s16x8 pa0 = *reinterpret_cast<const s16x8*>(&Ps[wid][0][r * 72 + c * 32 + g * 8]);
      s16x8 pa1 = *reinterpret_cast<const s16x8*>(&Ps[wid][1][r * 72 + c * 32 + g * 8]);
#pragma unroll
      for (int dn = 0; dn < 8; ++dn) {
        int d = dn * 16 + r;
        int pc = ((c * 4 + g) ^ (r & 7));               // phys chunk on read
        s16x8 vf = *reinterpret_cast<const s16x8*>(&Vt[d * 72 + (pc << 3)]);
        acc_o[0][dn] = MFMA_BF16(pa0, vf, acc_o[0][dn]);
        acc_o[1][dn] = MFMA_BF16(pa1, vf, acc_o[1][dn]);
      }
    }
  }

  // ---- deferred l reduction + epilogue (both sets) ----
#pragma unroll
  for (int s = 0; s < 2; ++s) {
#pragma unroll
    for (int reg = 0; reg < 4; ++reg) {
#pragma unroll
      for (int off = 1; off < 16; off <<= 1)
        l_run[s][reg] += __shfl_xor(l_run[s][reg], off);
      l_run[s][reg] = 1.f / l_run[s][reg];
    }
#pragma unroll
    for (int dn = 0; dn < 8; ++dn)
#pragma unroll
      for (int reg = 0; reg < 4; ++reg) {
        int row = q0 + s * 16 + g * 4 + reg;
        O[base + (size_t)row * EMB + dn * 16 + r] = f2bf(acc_o[s][dn][reg] * l_run[s][reg]);
      }
  }
}

__global__ void fill_f32(float* p, int n, float val) {
  int i = blockIdx.x * blockDim.x + threadIdx.x;
  if (i < n) p[i] = val;
}

// ---------------------------------------------------------------------------
extern "C" void kernel_launch(void* const* d_in, const int* in_sizes, int n_in,
                              void* d_out, int out_size, void* d_ws, size_t ws_size,
                              hipStream_t stream) {
  const float* q  = (const float*)d_in[0];
  const float* k  = (const float*)d_in[1];
  const float* v  = (const float*)d_in[2];
  const float* wq = (const float*)d_in[3];
  const float* wk = (const float*)d_in[4];
  const float* wv = (const float*)d_in[5];
  const float* wo = (const float*)d_in[6];
  float* out = (float*)d_out;

  bool ok = (n_in == 7) && out_size == 8388608;
  for (int i = 0; i < 3 && ok; ++i) ok = (in_sizes[i] == 8388608);
  for (int i = 3; i < 7 && ok; ++i) ok = (in_sizes[i] == 4194304);
  if (!ok) {
    fill_f32<<<(out_size + 255) / 256, 256, 0, stream>>>(out, out_size, 150.f);
    return;
  }

  const size_t NA = 8388608;
  const size_t NW = 4194304;
  const size_t NE = NA;
  const size_t need = (3 * NA + 4 * NW + 4 * NE) * sizeof(short); // 144 MiB
  if (ws_size < need) {
    fill_f32<<<(out_size + 255) / 256, 256, 0, stream>>>(out, out_size, 128.f);
    return;
  }

  short* bq  = (short*)d_ws;                 // cvt dst, contiguous
  short* bk  = bq + NA;
  short* bv  = bk + NA;
  short* bwq = bv + NA;
  short* bwk = bwq + NW;
  short* bwv = bwk + NW;
  short* bwo = bwv + NW;
  short* Qp  = bwo + NW;
  short* Kp  = Qp + NE;
  short* VpT = Kp + NE;                      // [2048 features][4096 tokens]
  short* Cx  = VpT + NE;

  dim3 blk(256);
  dim3 gg(16, 32);                           // (N/128, M/128) for M=4096,N=2048
  dim3 ggT(32, 16);                          // VpT: M'=2048, N'=4096
  dim3 ga(SL / 128, 32);                     // 512 blocks

  cvt_all<<<2048, 256, 0, stream>>>(q, k, v, wq, wk, wv, wo, bq);

  gemm_bt_bf16<false><<<gg, blk, 0, stream>>>(bq, bwq, Qp, 2048);
  gemm_bt_bf16<false><<<gg, blk, 0, stream>>>(bk, bwk, Kp, 2048);
  gemm_bt_bf16<false><<<ggT, blk, 0, stream>>>(bwv, bv, VpT, 4096);  // (v@Wv^T)^T
  attn<<<ga, blk, 0, stream>>>(Qp, Kp, VpT, Cx);
  gemm_bt_bf16<true><<<gg, blk, 0, stream>>>(Cx, bwo, out, 2048);
}